// Round 5
// baseline (422.730 us; speedup 1.0000x reference)
//
#include <hip/hip_runtime.h>
#include <math.h>

// Problem constants (B, C, H, W, D) = (4, 256, 32, 32, 32)
#define CCH   256
#define NTOT  32768                 // H*W*D
#define BB    4
#define SPLIT 128                   // K-split: grid = 3*4*128 = 1536 = 3.0x the 512
                                    // resident-block capacity (2/CU) -> no tail wave
#define KC    (NTOT / SPLIT)        // 256 n's per block
#define NK    32                    // LDS staging chunk
#define NSTAGES (KC / NK)           // 8
#define LDP   132                   // padded LDS row stride (132%32=4 -> 4-way writes; 132%4=0 -> aligned b128 reads)

__device__ inline float4 fma4(float s, float4 a, float4 c) {
    return make_float4(fmaf(s, a.x, c.x), fmaf(s, a.y, c.y),
                       fmaf(s, a.z, c.z), fmaf(s, a.w, c.w));
}

// ---------------------------------------------------------------------------
// K1: partial Gram matrix  a1[b] = xf[b] @ xf[b]^T  (symmetric: tiles 00,01,11)
//   tile 0 -> (c0=0,   d0=0)    diagonal
//   tile 1 -> (c0=0,   d0=128)  off-diagonal (mirrored later in K2)
//   tile 2 -> (c0=128, d0=128)  diagonal
// grid (3, B, SPLIT) = 1536 blocks, 256 threads, 8x8 micro-tile.
// Partials land in d_out (used as scratch; overwritten by K4 later).
// ---------------------------------------------------------------------------
__global__ __launch_bounds__(256, 2)
void k1_gram_partial(const float* __restrict__ x, float* __restrict__ part)
{
    const int tile = blockIdx.x;              // 0..2
    const int b    = blockIdx.y;              // 0..3
    const int s    = blockIdx.z;              // 0..SPLIT-1
    const int c0   = (tile == 2) ? 128 : 0;
    const int d0   = (tile == 0) ? 0 : 128;
    const bool diag = (tile != 1);

    const float* __restrict__ xb = x + (size_t)b * CCH * NTOT;
    const int n0 = s * KC;

    __shared__ __align__(16) float as[NK][LDP];   // [n][c] layout, padded
    __shared__ __align__(16) float bs[NK][LDP];

    const int tid = threadIdx.x;
    const int tx  = tid & 15;     // d-direction (16 threads)
    const int ty  = tid >> 4;     // c-direction (16 threads)
    const int lr  = tid >> 3;     // load row 0..31
    const int lq  = tid & 7;      // load float4-col 0..7

    float acc[8][8];
#pragma unroll
    for (int i = 0; i < 8; ++i)
#pragma unroll
        for (int j = 0; j < 8; ++j) acc[i][j] = 0.f;

    for (int st = 0; st < NSTAGES; ++st) {
        const int nb = n0 + st * NK;
        // ---- stage global -> LDS (transposed write: [n][c]) ----
#pragma unroll
        for (int k = 0; k < 4; ++k) {
            const int r = lr + 32 * k;
            const float4 va =
                *(const float4*)&xb[(size_t)(c0 + r) * NTOT + nb + lq * 4];
            as[lq * 4 + 0][r] = va.x;
            as[lq * 4 + 1][r] = va.y;
            as[lq * 4 + 2][r] = va.z;
            as[lq * 4 + 3][r] = va.w;
            if (!diag) {
                const float4 vb =
                    *(const float4*)&xb[(size_t)(d0 + r) * NTOT + nb + lq * 4];
                bs[lq * 4 + 0][r] = vb.x;
                bs[lq * 4 + 1][r] = vb.y;
                bs[lq * 4 + 2][r] = vb.z;
                bs[lq * 4 + 3][r] = vb.w;
            }
        }
        __syncthreads();

        const float* __restrict__ abase = &as[0][0];
        const float* __restrict__ bbase = diag ? &as[0][0] : &bs[0][0];

#pragma unroll 8
        for (int n = 0; n < NK; ++n) {
            const float4 a0 = *(const float4*)&abase[n * LDP + ty * 8];
            const float4 a1 = *(const float4*)&abase[n * LDP + ty * 8 + 4];
            const float4 b0 = *(const float4*)&bbase[n * LDP + tx * 8];
            const float4 b1 = *(const float4*)&bbase[n * LDP + tx * 8 + 4];
            const float av[8] = {a0.x, a0.y, a0.z, a0.w, a1.x, a1.y, a1.z, a1.w};
            const float bv[8] = {b0.x, b0.y, b0.z, b0.w, b1.x, b1.y, b1.z, b1.w};
#pragma unroll
            for (int i = 0; i < 8; ++i)
#pragma unroll
                for (int j = 0; j < 8; ++j)
                    acc[i][j] = fmaf(av[i], bv[j], acc[i][j]);
        }
        __syncthreads();
    }

    float* __restrict__ pdst =
        part + (((size_t)s * BB + b) * 3 + tile) * (128 * 128);
#pragma unroll
    for (int i = 0; i < 8; ++i) {
        const float4 v0 = make_float4(acc[i][0], acc[i][1], acc[i][2], acc[i][3]);
        const float4 v1 = make_float4(acc[i][4], acc[i][5], acc[i][6], acc[i][7]);
        *(float4*)&pdst[(ty * 8 + i) * 128 + tx * 8]     = v0;
        *(float4*)&pdst[(ty * 8 + i) * 128 + tx * 8 + 4] = v1;
    }
}

// ---------------------------------------------------------------------------
// K2: reduce the SPLIT partials -> a1[b][c][d] (in ws), mirroring tile 1.
// 768 blocks x 256 threads; reads coalesced (stride between splits).
// ---------------------------------------------------------------------------
__global__ __launch_bounds__(256)
void k2_reduce(const float* __restrict__ part, float* __restrict__ a1)
{
    const int gi   = blockIdx.x * 256 + threadIdx.x;   // 0 .. 196607
    const int ld   = gi & 127;
    const int lc   = (gi >> 7) & 127;
    const int t    = gi >> 14;                         // 0..11
    const int tile = t % 3;
    const int b    = t / 3;

    const size_t off    = ((size_t)b * 3 + tile) * (128 * 128) + lc * 128 + ld;
    const size_t stride = (size_t)BB * 3 * (128 * 128);
    float sum = 0.f;
#pragma unroll 8
    for (int s = 0; s < SPLIT; ++s) sum += part[off + s * stride];

    const int c0 = (tile == 2) ? 128 : 0;
    const int d0 = (tile == 0) ? 0 : 128;
    const int c = c0 + lc, d = d0 + ld;
    a1[((size_t)b << 16) + (c << 8) + d] = sum;
    if (tile == 1)                                      // mirror (symmetric)
        a1[((size_t)b << 16) + ((128 + ld) << 8) + lc] = sum;
}

// ---------------------------------------------------------------------------
// K3: one block per (b, row c): affinity row = a1[c,:] @ a1, then replicate
// the reference's exact softmax path:
//   M = rowmax(aff); an = M - aff; m2 = rowmax(an); p = exp(an-m2)/sum
// ---------------------------------------------------------------------------
__global__ __launch_bounds__(256)
void k3_softmax(const float* __restrict__ a1, float* __restrict__ p)
{
    const int c = blockIdx.x;
    const int b = blockIdx.y;
    const float* __restrict__ A = a1 + ((size_t)b << 16);

    __shared__ float arow[256];
    __shared__ float red[256];
    const int e = threadIdx.x;
    arow[e] = A[(c << 8) + e];
    __syncthreads();

    float aff = 0.f;
#pragma unroll 8
    for (int d = 0; d < 256; ++d)
        aff = fmaf(arow[d], A[(d << 8) + e], aff);

    red[e] = aff; __syncthreads();
    for (int s2 = 128; s2 > 0; s2 >>= 1) {
        if (e < s2) red[e] = fmaxf(red[e], red[e + s2]);
        __syncthreads();
    }
    const float M = red[0];
    __syncthreads();

    const float an = M - aff;
    red[e] = an; __syncthreads();
    for (int s2 = 128; s2 > 0; s2 >>= 1) {
        if (e < s2) red[e] = fmaxf(red[e], red[e + s2]);
        __syncthreads();
    }
    const float m2 = red[0];
    __syncthreads();

    const float ex = expf(an - m2);
    red[e] = ex; __syncthreads();
    for (int s2 = 128; s2 > 0; s2 >>= 1) {
        if (e < s2) red[e] += red[e + s2];
        __syncthreads();
    }
    const float Z = red[0];
    p[((size_t)b << 16) + (c << 8) + e] = ex / Z;
}

// ---------------------------------------------------------------------------
// K4: out = gamma * (p @ xf) + x.  p rows are (numerically exact) near-one-hot:
// skip p==0 terms with a block-uniform branch -> memory-bound gather.
// grid (8 n-chunks, C, B), 256 threads, 16 floats/thread per chunk.
// ---------------------------------------------------------------------------
#define NCHUNK 8
#define CH4    (NTOT / NCHUNK / 4)   // 1024 float4 per chunk

__global__ __launch_bounds__(256)
void k4_out(const float* __restrict__ x, const float* __restrict__ p,
            const float* __restrict__ gamma, float* __restrict__ out)
{
    const int ch = blockIdx.x;   // 0..7
    const int c  = blockIdx.y;   // 0..255
    const int b  = blockIdx.z;   // 0..3
    const float* __restrict__ xb = x + (size_t)b * CCH * NTOT;

    __shared__ float prow[256];
    const int tid = threadIdx.x;
    prow[tid] = p[((size_t)b << 16) + (c << 8) + tid];
    __syncthreads();

    const size_t nb4 = (size_t)ch * CH4;
    float4 acc0 = make_float4(0, 0, 0, 0);
    float4 acc1 = acc0, acc2 = acc0, acc3 = acc0;

    for (int d = 0; d < 256; ++d) {
        const float sv = prow[d];
        if (sv != 0.f) {                               // block-uniform branch
            const float4* __restrict__ r =
                (const float4*)(xb + (size_t)d * NTOT) + nb4;
            acc0 = fma4(sv, r[tid],       acc0);
            acc1 = fma4(sv, r[tid + 256], acc1);
            acc2 = fma4(sv, r[tid + 512], acc2);
            acc3 = fma4(sv, r[tid + 768], acc3);
        }
    }

    const float g = gamma[0];
    const float4* __restrict__ xr = (const float4*)(xb + (size_t)c * NTOT) + nb4;
    float4* __restrict__ o =
        (float4*)(out + ((size_t)b * CCH + c) * NTOT) + nb4;
    o[tid]       = fma4(g, acc0, xr[tid]);
    o[tid + 256] = fma4(g, acc1, xr[tid + 256]);
    o[tid + 512] = fma4(g, acc2, xr[tid + 512]);
    o[tid + 768] = fma4(g, acc3, xr[tid + 768]);
}

// ---------------------------------------------------------------------------
extern "C" void kernel_launch(void* const* d_in, const int* in_sizes, int n_in,
                              void* d_out, int out_size, void* d_ws, size_t ws_size,
                              hipStream_t stream)
{
    const float* x     = (const float*)d_in[0];
    const float* gamma = (const float*)d_in[1];
    float* out = (float*)d_out;

    // d_out doubles as scratch for the Gram partials (SPLIT=128: 100.7 MB
    // < 134.2 MB of d_out); K2 consumes them before K4 overwrites d_out
    // (stream-ordered).
    float* part = out;
    float* a1 = (float*)d_ws;                      // B*256*256 floats (1 MiB)
    float* p  = a1 + (size_t)BB * CCH * CCH;       // B*256*256 floats (1 MiB)

    k1_gram_partial<<<dim3(3, BB, SPLIT), 256, 0, stream>>>(x, part);
    k2_reduce      <<<dim3(768),          256, 0, stream>>>(part, a1);
    k3_softmax     <<<dim3(CCH, BB),      256, 0, stream>>>(a1, p);
    k4_out         <<<dim3(NCHUNK, CCH, BB), 256, 0, stream>>>(x, p, gamma, out);
}

// Round 6
// 403.352 us; speedup vs baseline: 1.0480x; 1.0480x over previous
//
#include <hip/hip_runtime.h>
#include <math.h>

// Problem constants (B, C, H, W, D) = (4, 256, 32, 32, 32)
#define CCH   256
#define NTOT  32768                 // H*W*D
#define BB    4
#define SPLIT 64                    // grid = 3*4*64 = 768 = exactly 3 blocks/CU (uniform, no tail)
#define KC    (NTOT / SPLIT)        // 512 n's per block
#define NK    32                    // LDS staging chunk
#define NSTAGES (KC / NK)           // 16
#define LDP   132                   // padded LDS row stride (132%32=4 -> 4-way writes; 132%4=0 -> aligned b128 reads)
#define NZCAP 16                    // nonzero-list capacity per softmax row (dense fallback beyond)

__device__ inline float4 fma4(float s, float4 a, float4 c) {
    return make_float4(fmaf(s, a.x, c.x), fmaf(s, a.y, c.y),
                       fmaf(s, a.z, c.z), fmaf(s, a.w, c.w));
}

// ---------------------------------------------------------------------------
// K1: partial Gram matrix  a1[b] = xf[b] @ xf[b]^T  (symmetric: tiles 00,01,11)
// grid (3, B, SPLIT) = 768 blocks @ 3 blocks/CU, 256 threads, 8x8 micro-tile.
// Partials land in d_out (used as scratch; overwritten by K4 later).
// ---------------------------------------------------------------------------
__global__ __launch_bounds__(256, 3)
void k1_gram_partial(const float* __restrict__ x, float* __restrict__ part)
{
    const int tile = blockIdx.x;              // 0..2
    const int b    = blockIdx.y;              // 0..3
    const int s    = blockIdx.z;              // 0..SPLIT-1
    const int c0   = (tile == 2) ? 128 : 0;
    const int d0   = (tile == 0) ? 0 : 128;
    const bool diag = (tile != 1);

    const float* __restrict__ xb = x + (size_t)b * CCH * NTOT;
    const int n0 = s * KC;

    __shared__ __align__(16) float as[NK][LDP];   // [n][c] layout, padded
    __shared__ __align__(16) float bs[NK][LDP];

    const int tid = threadIdx.x;
    const int tx  = tid & 15;     // d-direction (16 threads)
    const int ty  = tid >> 4;     // c-direction (16 threads)
    const int lr  = tid >> 3;     // load row 0..31
    const int lq  = tid & 7;      // load float4-col 0..7

    float acc[8][8];
#pragma unroll
    for (int i = 0; i < 8; ++i)
#pragma unroll
        for (int j = 0; j < 8; ++j) acc[i][j] = 0.f;

    for (int st = 0; st < NSTAGES; ++st) {
        const int nb = n0 + st * NK;
        // ---- stage global -> LDS (transposed write: [n][c]) ----
#pragma unroll
        for (int k = 0; k < 4; ++k) {
            const int r = lr + 32 * k;
            const float4 va =
                *(const float4*)&xb[(size_t)(c0 + r) * NTOT + nb + lq * 4];
            as[lq * 4 + 0][r] = va.x;
            as[lq * 4 + 1][r] = va.y;
            as[lq * 4 + 2][r] = va.z;
            as[lq * 4 + 3][r] = va.w;
            if (!diag) {
                const float4 vb =
                    *(const float4*)&xb[(size_t)(d0 + r) * NTOT + nb + lq * 4];
                bs[lq * 4 + 0][r] = vb.x;
                bs[lq * 4 + 1][r] = vb.y;
                bs[lq * 4 + 2][r] = vb.z;
                bs[lq * 4 + 3][r] = vb.w;
            }
        }
        __syncthreads();

        const float* __restrict__ abase = &as[0][0];
        const float* __restrict__ bbase = diag ? &as[0][0] : &bs[0][0];

#pragma unroll 8
        for (int n = 0; n < NK; ++n) {
            const float4 a0 = *(const float4*)&abase[n * LDP + ty * 8];
            const float4 a1 = *(const float4*)&abase[n * LDP + ty * 8 + 4];
            const float4 b0 = *(const float4*)&bbase[n * LDP + tx * 8];
            const float4 b1 = *(const float4*)&bbase[n * LDP + tx * 8 + 4];
            const float av[8] = {a0.x, a0.y, a0.z, a0.w, a1.x, a1.y, a1.z, a1.w};
            const float bv[8] = {b0.x, b0.y, b0.z, b0.w, b1.x, b1.y, b1.z, b1.w};
#pragma unroll
            for (int i = 0; i < 8; ++i)
#pragma unroll
                for (int j = 0; j < 8; ++j)
                    acc[i][j] = fmaf(av[i], bv[j], acc[i][j]);
        }
        __syncthreads();
    }

    float* __restrict__ pdst =
        part + (((size_t)s * BB + b) * 3 + tile) * (128 * 128);
#pragma unroll
    for (int i = 0; i < 8; ++i) {
        const float4 v0 = make_float4(acc[i][0], acc[i][1], acc[i][2], acc[i][3]);
        const float4 v1 = make_float4(acc[i][4], acc[i][5], acc[i][6], acc[i][7]);
        *(float4*)&pdst[(ty * 8 + i) * 128 + tx * 8]     = v0;
        *(float4*)&pdst[(ty * 8 + i) * 128 + tx * 8 + 4] = v1;
    }
}

// ---------------------------------------------------------------------------
// K2: reduce the SPLIT partials -> a1[b][c][d] (in ws), mirroring tile 1.
// ---------------------------------------------------------------------------
__global__ __launch_bounds__(256)
void k2_reduce(const float* __restrict__ part, float* __restrict__ a1)
{
    const int gi   = blockIdx.x * 256 + threadIdx.x;   // 0 .. 196607
    const int ld   = gi & 127;
    const int lc   = (gi >> 7) & 127;
    const int t    = gi >> 14;                         // 0..11
    const int tile = t % 3;
    const int b    = t / 3;

    const size_t off    = ((size_t)b * 3 + tile) * (128 * 128) + lc * 128 + ld;
    const size_t stride = (size_t)BB * 3 * (128 * 128);
    float sum = 0.f;
#pragma unroll 8
    for (int s = 0; s < SPLIT; ++s) sum += part[off + s * stride];

    const int c0 = (tile == 2) ? 128 : 0;
    const int d0 = (tile == 0) ? 0 : 128;
    const int c = c0 + lc, d = d0 + ld;
    a1[((size_t)b << 16) + (c << 8) + d] = sum;
    if (tile == 1)                                      // mirror (symmetric)
        a1[((size_t)b << 16) + ((128 + ld) << 8) + lc] = sum;
}

// ---------------------------------------------------------------------------
// K3: one block per (b, row c): affinity row = a1[c,:] @ a1, then the
// reference's exact softmax path:
//   M = rowmax(aff); an = M - aff; m2 = rowmax(an); p = exp(an-m2)/sum
// Additionally emits the nonzero list (cnt/idx/val) so K4 avoids a 256-scan.
// p itself is still written for the (unlikely) cnt>NZCAP dense fallback.
// ---------------------------------------------------------------------------
__global__ __launch_bounds__(256)
void k3_softmax(const float* __restrict__ a1, float* __restrict__ p,
                int* __restrict__ nzcnt, int* __restrict__ nzidx,
                float* __restrict__ nzval)
{
    const int c = blockIdx.x;
    const int b = blockIdx.y;
    const int bc = (b << 8) + c;
    const float* __restrict__ A = a1 + ((size_t)b << 16);

    __shared__ float arow[256];
    __shared__ float red[256];
    const int e = threadIdx.x;
    arow[e] = A[(c << 8) + e];
    __syncthreads();

    float aff = 0.f;
#pragma unroll 8
    for (int d = 0; d < 256; ++d)
        aff = fmaf(arow[d], A[(d << 8) + e], aff);

    red[e] = aff; __syncthreads();
    for (int s2 = 128; s2 > 0; s2 >>= 1) {
        if (e < s2) red[e] = fmaxf(red[e], red[e + s2]);
        __syncthreads();
    }
    const float M = red[0];
    __syncthreads();

    const float an = M - aff;
    red[e] = an; __syncthreads();
    for (int s2 = 128; s2 > 0; s2 >>= 1) {
        if (e < s2) red[e] = fmaxf(red[e], red[e + s2]);
        __syncthreads();
    }
    const float m2 = red[0];
    __syncthreads();

    const float ex = expf(an - m2);
    red[e] = ex; __syncthreads();
    for (int s2 = 128; s2 > 0; s2 >>= 1) {
        if (e < s2) red[e] += red[e + s2];
        __syncthreads();
    }
    const float Z = red[0];
    const float pv = ex / Z;                 // identical numeric path to before
    p[((size_t)bc << 8) + e] = pv;

    // ---- nonzero list (deterministic ascending order) ----
    __syncthreads();                         // red[] free; arow[] free
    arow[e] = pv;
    __syncthreads();
    if (e == 0) {
        int k = 0;
        for (int d = 0; d < 256; ++d) {
            const float v = arow[d];
            if (v > 0.f) {
                if (k < NZCAP) { nzidx[bc * NZCAP + k] = d; nzval[bc * NZCAP + k] = v; }
                ++k;
            }
        }
        nzcnt[bc] = k;
    }
}

// ---------------------------------------------------------------------------
// K4: out = gamma * (p @ xf) + x, using the nonzero list (typically 1 entry).
// grid (8 n-chunks, C, B), 256 threads, 16 floats/thread per chunk.
// ---------------------------------------------------------------------------
#define NCHUNK 8
#define CH4    (NTOT / NCHUNK / 4)   // 1024 float4 per chunk

__global__ __launch_bounds__(256)
void k4_out(const float* __restrict__ x, const float* __restrict__ p,
            const int* __restrict__ nzcnt, const int* __restrict__ nzidx,
            const float* __restrict__ nzval,
            const float* __restrict__ gamma, float* __restrict__ out)
{
    const int ch = blockIdx.x;   // 0..7
    const int c  = blockIdx.y;   // 0..255
    const int b  = blockIdx.z;   // 0..3
    const int bc = (b << 8) + c;
    const float* __restrict__ xb = x + (size_t)b * CCH * NTOT;

    const int tid = threadIdx.x;
    const size_t nb4 = (size_t)ch * CH4;
    float4 acc0 = make_float4(0, 0, 0, 0);
    float4 acc1 = acc0, acc2 = acc0, acc3 = acc0;

    const int k = nzcnt[bc];
    if (k <= NZCAP) {
        for (int j = 0; j < k; ++j) {        // ascending d, matches ref order
            const int   d  = nzidx[bc * NZCAP + j];
            const float sv = nzval[bc * NZCAP + j];
            const float4* __restrict__ r =
                (const float4*)(xb + (size_t)d * NTOT) + nb4;
            acc0 = fma4(sv, r[tid],       acc0);
            acc1 = fma4(sv, r[tid + 256], acc1);
            acc2 = fma4(sv, r[tid + 512], acc2);
            acc3 = fma4(sv, r[tid + 768], acc3);
        }
    } else {                                  // dense fallback (always correct)
        for (int d = 0; d < 256; ++d) {
            const float sv = p[((size_t)bc << 8) + d];
            if (sv != 0.f) {
                const float4* __restrict__ r =
                    (const float4*)(xb + (size_t)d * NTOT) + nb4;
                acc0 = fma4(sv, r[tid],       acc0);
                acc1 = fma4(sv, r[tid + 256], acc1);
                acc2 = fma4(sv, r[tid + 512], acc2);
                acc3 = fma4(sv, r[tid + 768], acc3);
            }
        }
    }

    const float g = gamma[0];
    const float4* __restrict__ xr = (const float4*)(xb + (size_t)c * NTOT) + nb4;
    float4* __restrict__ o =
        (float4*)(out + ((size_t)b * CCH + c) * NTOT) + nb4;
    o[tid]       = fma4(g, acc0, xr[tid]);
    o[tid + 256] = fma4(g, acc1, xr[tid + 256]);
    o[tid + 512] = fma4(g, acc2, xr[tid + 512]);
    o[tid + 768] = fma4(g, acc3, xr[tid + 768]);
}

// ---------------------------------------------------------------------------
extern "C" void kernel_launch(void* const* d_in, const int* in_sizes, int n_in,
                              void* d_out, int out_size, void* d_ws, size_t ws_size,
                              hipStream_t stream)
{
    const float* x     = (const float*)d_in[0];
    const float* gamma = (const float*)d_in[1];
    float* out = (float*)d_out;

    // d_out doubles as scratch for the Gram partials (SPLIT=64: 50.3 MB
    // < 134.2 MB of d_out); K2 consumes them before K4 overwrites d_out.
    float* part = out;
    float* a1    = (float*)d_ws;                       // 1 MiB
    float* p     = a1 + (size_t)BB * CCH * CCH;        // 1 MiB
    int*   nzcnt = (int*)(p + (size_t)BB * CCH * CCH); // 4 KiB
    int*   nzidx = nzcnt + BB * CCH;                   // 64 KiB
    float* nzval = (float*)(nzidx + BB * CCH * NZCAP); // 64 KiB

    k1_gram_partial<<<dim3(3, BB, SPLIT), 256, 0, stream>>>(x, part);
    k2_reduce      <<<dim3(768),          256, 0, stream>>>(part, a1);
    k3_softmax     <<<dim3(CCH, BB),      256, 0, stream>>>(a1, p, nzcnt, nzidx, nzval);
    k4_out         <<<dim3(NCHUNK, CCH, BB), 256, 0, stream>>>(x, p, nzcnt, nzidx, nzval, gamma, out);
}

// Round 8
// 318.218 us; speedup vs baseline: 1.3284x; 1.2675x over previous
//
#include <hip/hip_runtime.h>
#include <math.h>

// Problem constants (B, C, H, W, D) = (4, 256, 32, 32, 32)
#define CCH   256
#define NTOT  32768                 // H*W*D
#define BB    4
#define SPLIT 64                    // K-split: grid = 3*4*64 = 768 blocks = 3/CU
#define KC    (NTOT / SPLIT)        // 512 k's per block
#define KN    32                    // k-chunk staged in LDS per iteration
#define NSTAGES (KC / KN)           // 16
#define LDK   40                    // LDS row stride in bf16 units (80 B, 16B-aligned rows)
#define NZCAP 16                    // nonzero-list capacity per softmax row

typedef __attribute__((ext_vector_type(8)))  short short8v;   // 8 bf16 = 4 VGPRs
typedef __attribute__((ext_vector_type(16))) float f32x16;    // 32x32 MFMA acc

__device__ inline float4 fma4(float s, float4 a, float4 c) {
    return make_float4(fmaf(s, a.x, c.x), fmaf(s, a.y, c.y),
                       fmaf(s, a.z, c.z), fmaf(s, a.w, c.w));
}

// split x into hi (truncated bf16) + lo (RNE bf16 of remainder); x ~ hi+lo with
// residual ~2^-16*|x| -- far below the ~3.5e6 affinity argmin margins.
__device__ inline void cvt2(float x, unsigned short& h, unsigned short& l) {
    unsigned int u = __float_as_uint(x);
    h = (unsigned short)(u >> 16);
    float hf = __uint_as_float(u & 0xFFFF0000u);
    float lf = x - hf;
    unsigned int ul = __float_as_uint(lf);
    ul += 0x7FFFu + ((ul >> 16) & 1u);
    l = (unsigned short)(ul >> 16);
}

// ---------------------------------------------------------------------------
// K1: partial Gram a1[b] = xf[b] @ xf[b]^T via bf16 split MFMA (HH+HL+LH).
// Symmetric 3-tile scheme: tile0 (0,0) diag, tile1 (0,128) offdiag, tile2
// (128,128) diag. grid (3, B, SPLIT), 256 threads (4 waves), each wave owns a
// 64x64 quadrant of the 128x128 output = 2x2 MFMA tiles of 32x32.
// Partials (fp32) land in d_out scratch; K2 reduces them (unchanged format).
// ---------------------------------------------------------------------------
__global__ __launch_bounds__(256, 3)
void k1_gram_partial(const float* __restrict__ x, float* __restrict__ part)
{
    const int tile = blockIdx.x;              // 0..2
    const int b    = blockIdx.y;              // 0..3
    const int s    = blockIdx.z;              // 0..SPLIT-1
    const int c0   = (tile == 2) ? 128 : 0;
    const int d0   = (tile == 0) ? 0 : 128;
    const bool diag = (tile != 1);

    const float* __restrict__ xb = x + (size_t)b * CCH * NTOT;
    const int n0 = s * KC;

    // rows [0,128) = A channels (c0+r); rows [128,256) = B channels (d0+r), offdiag only
    __shared__ __align__(16) short sH[256][LDK];
    __shared__ __align__(16) short sL[256][LDK];

    const int tid  = threadIdx.x;
    const int wid  = tid >> 6;      // wave 0..3
    const int wr   = wid >> 1;      // wave row quadrant (0,1)
    const int wc   = wid & 1;       // wave col quadrant (0,1)
    const int lane = tid & 63;
    const int l31  = lane & 31;
    const int kh   = lane >> 5;     // k-half selector (0,1)

    f32x16 acc00 = {0.f}, acc01 = {0.f}, acc10 = {0.f}, acc11 = {0.f};

    const int rowsTotal = diag ? 128 : 256;
    const int brow0 = diag ? 0 : 128;          // LDS base row for B-operand

    for (int st = 0; st < NSTAGES; ++st) {
        const int nb = n0 + st * KN;
        __syncthreads();                       // protect LDS from prev reads
        // ---- stage: load fp32, split to hi/lo bf16, write LDS ----
        for (int it = 0; it < rowsTotal / 32; ++it) {
            const int r  = it * 32 + (tid >> 3);    // LDS row
            const int k0 = (tid & 7) * 4;           // k offset
            const int gr = (r < 128) ? (c0 + r) : (d0 + r - 128);
            const float4 v = *(const float4*)&xb[(size_t)gr * NTOT + nb + k0];
            unsigned short h0,h1,h2,h3, l0,l1,l2,l3;
            cvt2(v.x, h0, l0); cvt2(v.y, h1, l1);
            cvt2(v.z, h2, l2); cvt2(v.w, h3, l3);
            *(short4*)&sH[r][k0] = make_short4((short)h0,(short)h1,(short)h2,(short)h3);
            *(short4*)&sL[r][k0] = make_short4((short)l0,(short)l1,(short)l2,(short)l3);
        }
        __syncthreads();

        // ---- compute: 2 K-steps of 16, 2x2 tiles, 3 passes each ----
#pragma unroll
        for (int kk = 0; kk < KN; kk += 16) {
            const int koff = kk + kh * 8;
            const int ar0 = wr * 64 + l31;            // A rows (LDS)
            const int br0 = brow0 + wc * 64 + l31;    // B rows (LDS)
            const short8v a0h = *(const short8v*)&sH[ar0     ][koff];
            const short8v a0l = *(const short8v*)&sL[ar0     ][koff];
            const short8v a1h = *(const short8v*)&sH[ar0 + 32][koff];
            const short8v a1l = *(const short8v*)&sL[ar0 + 32][koff];
            const short8v b0h = *(const short8v*)&sH[br0     ][koff];
            const short8v b0l = *(const short8v*)&sL[br0     ][koff];
            const short8v b1h = *(const short8v*)&sH[br0 + 32][koff];
            const short8v b1l = *(const short8v*)&sL[br0 + 32][koff];

            acc00 = __builtin_amdgcn_mfma_f32_32x32x16_bf16(a0h, b0h, acc00, 0, 0, 0);
            acc00 = __builtin_amdgcn_mfma_f32_32x32x16_bf16(a0h, b0l, acc00, 0, 0, 0);
            acc00 = __builtin_amdgcn_mfma_f32_32x32x16_bf16(a0l, b0h, acc00, 0, 0, 0);

            acc01 = __builtin_amdgcn_mfma_f32_32x32x16_bf16(a0h, b1h, acc01, 0, 0, 0);
            acc01 = __builtin_amdgcn_mfma_f32_32x32x16_bf16(a0h, b1l, acc01, 0, 0, 0);
            acc01 = __builtin_amdgcn_mfma_f32_32x32x16_bf16(a0l, b1h, acc01, 0, 0, 0);

            acc10 = __builtin_amdgcn_mfma_f32_32x32x16_bf16(a1h, b0h, acc10, 0, 0, 0);
            acc10 = __builtin_amdgcn_mfma_f32_32x32x16_bf16(a1h, b0l, acc10, 0, 0, 0);
            acc10 = __builtin_amdgcn_mfma_f32_32x32x16_bf16(a1l, b0h, acc10, 0, 0, 0);

            acc11 = __builtin_amdgcn_mfma_f32_32x32x16_bf16(a1h, b1h, acc11, 0, 0, 0);
            acc11 = __builtin_amdgcn_mfma_f32_32x32x16_bf16(a1h, b1l, acc11, 0, 0, 0);
            acc11 = __builtin_amdgcn_mfma_f32_32x32x16_bf16(a1l, b1h, acc11, 0, 0, 0);
        }
    }

    // ---- write 128x128 fp32 partial tile; C/D map: col=l&31, row=(q&3)+8(q>>2)+4*kh
    float* __restrict__ pdst =
        part + (((size_t)s * BB + b) * 3 + tile) * (128 * 128);
#define WRITE_TILE(ACC, TI, TJ)                                              \
    _Pragma("unroll")                                                        \
    for (int q = 0; q < 16; ++q) {                                           \
        const int row = wr * 64 + (TI) * 32 + (q & 3) + 8 * (q >> 2) + 4 * kh; \
        const int col = wc * 64 + (TJ) * 32 + l31;                           \
        pdst[row * 128 + col] = (ACC)[q];                                    \
    }
    WRITE_TILE(acc00, 0, 0)
    WRITE_TILE(acc01, 0, 1)
    WRITE_TILE(acc10, 1, 0)
    WRITE_TILE(acc11, 1, 1)
#undef WRITE_TILE
}

// ---------------------------------------------------------------------------
// K2: reduce the SPLIT partials -> a1[b][c][d] (in ws), mirroring tile 1.
// ---------------------------------------------------------------------------
__global__ __launch_bounds__(256)
void k2_reduce(const float* __restrict__ part, float* __restrict__ a1)
{
    const int gi   = blockIdx.x * 256 + threadIdx.x;   // 0 .. 196607
    const int ld   = gi & 127;
    const int lc   = (gi >> 7) & 127;
    const int t    = gi >> 14;                         // 0..11
    const int tile = t % 3;
    const int b    = t / 3;

    const size_t off    = ((size_t)b * 3 + tile) * (128 * 128) + lc * 128 + ld;
    const size_t stride = (size_t)BB * 3 * (128 * 128);
    float sum = 0.f;
#pragma unroll 8
    for (int s = 0; s < SPLIT; ++s) sum += part[off + s * stride];

    const int c0 = (tile == 2) ? 128 : 0;
    const int d0 = (tile == 0) ? 0 : 128;
    const int c = c0 + lc, d = d0 + ld;
    a1[((size_t)b << 16) + (c << 8) + d] = sum;
    if (tile == 1)                                      // mirror (symmetric)
        a1[((size_t)b << 16) + ((128 + ld) << 8) + lc] = sum;
}

// ---------------------------------------------------------------------------
// K3: one block per (b, row c): affinity row = a1[c,:] @ a1, then the
// reference's exact softmax path; also emits nonzero list for K4.
// ---------------------------------------------------------------------------
__global__ __launch_bounds__(256)
void k3_softmax(const float* __restrict__ a1, float* __restrict__ p,
                int* __restrict__ nzcnt, int* __restrict__ nzidx,
                float* __restrict__ nzval)
{
    const int c = blockIdx.x;
    const int b = blockIdx.y;
    const int bc = (b << 8) + c;
    const float* __restrict__ A = a1 + ((size_t)b << 16);

    __shared__ float arow[256];
    __shared__ float red[256];
    const int e = threadIdx.x;
    arow[e] = A[(c << 8) + e];
    __syncthreads();

    float aff = 0.f;
#pragma unroll 8
    for (int d = 0; d < 256; ++d)
        aff = fmaf(arow[d], A[(d << 8) + e], aff);

    red[e] = aff; __syncthreads();
    for (int s2 = 128; s2 > 0; s2 >>= 1) {
        if (e < s2) red[e] = fmaxf(red[e], red[e + s2]);
        __syncthreads();
    }
    const float M = red[0];
    __syncthreads();

    const float an = M - aff;
    red[e] = an; __syncthreads();
    for (int s2 = 128; s2 > 0; s2 >>= 1) {
        if (e < s2) red[e] = fmaxf(red[e], red[e + s2]);
        __syncthreads();
    }
    const float m2 = red[0];
    __syncthreads();

    const float ex = expf(an - m2);
    red[e] = ex; __syncthreads();
    for (int s2 = 128; s2 > 0; s2 >>= 1) {
        if (e < s2) red[e] += red[e + s2];
        __syncthreads();
    }
    const float Z = red[0];
    const float pv = ex / Z;
    p[((size_t)bc << 8) + e] = pv;

    __syncthreads();
    arow[e] = pv;
    __syncthreads();
    if (e == 0) {
        int k = 0;
        for (int d = 0; d < 256; ++d) {
            const float v = arow[d];
            if (v > 0.f) {
                if (k < NZCAP) { nzidx[bc * NZCAP + k] = d; nzval[bc * NZCAP + k] = v; }
                ++k;
            }
        }
        nzcnt[bc] = k;
    }
}

// ---------------------------------------------------------------------------
// K4: out = gamma * (p @ xf) + x via the nonzero list (typically 1 entry).
// ---------------------------------------------------------------------------
#define NCHUNK 8
#define CH4    (NTOT / NCHUNK / 4)   // 1024 float4 per chunk

__global__ __launch_bounds__(256)
void k4_out(const float* __restrict__ x, const float* __restrict__ p,
            const int* __restrict__ nzcnt, const int* __restrict__ nzidx,
            const float* __restrict__ nzval,
            const float* __restrict__ gamma, float* __restrict__ out)
{
    const int ch = blockIdx.x;   // 0..7
    const int c  = blockIdx.y;   // 0..255
    const int b  = blockIdx.z;   // 0..3
    const int bc = (b << 8) + c;
    const float* __restrict__ xb = x + (size_t)b * CCH * NTOT;

    const int tid = threadIdx.x;
    const size_t nb4 = (size_t)ch * CH4;
    float4 acc0 = make_float4(0, 0, 0, 0);
    float4 acc1 = acc0, acc2 = acc0, acc3 = acc0;

    const int k = nzcnt[bc];
    if (k <= NZCAP) {
        for (int j = 0; j < k; ++j) {        // ascending d, matches ref order
            const int   d  = nzidx[bc * NZCAP + j];
            const float sv = nzval[bc * NZCAP + j];
            const float4* __restrict__ r =
                (const float4*)(xb + (size_t)d * NTOT) + nb4;
            acc0 = fma4(sv, r[tid],       acc0);
            acc1 = fma4(sv, r[tid + 256], acc1);
            acc2 = fma4(sv, r[tid + 512], acc2);
            acc3 = fma4(sv, r[tid + 768], acc3);
        }
    } else {                                  // dense fallback (always correct)
        for (int d = 0; d < 256; ++d) {
            const float sv = p[((size_t)bc << 8) + d];
            if (sv != 0.f) {
                const float4* __restrict__ r =
                    (const float4*)(xb + (size_t)d * NTOT) + nb4;
                acc0 = fma4(sv, r[tid],       acc0);
                acc1 = fma4(sv, r[tid + 256], acc1);
                acc2 = fma4(sv, r[tid + 512], acc2);
                acc3 = fma4(sv, r[tid + 768], acc3);
            }
        }
    }

    const float g = gamma[0];
    const float4* __restrict__ xr = (const float4*)(xb + (size_t)c * NTOT) + nb4;
    float4* __restrict__ o =
        (float4*)(out + ((size_t)b * CCH + c) * NTOT) + nb4;
    o[tid]       = fma4(g, acc0, xr[tid]);
    o[tid + 256] = fma4(g, acc1, xr[tid + 256]);
    o[tid + 512] = fma4(g, acc2, xr[tid + 512]);
    o[tid + 768] = fma4(g, acc3, xr[tid + 768]);
}

// ---------------------------------------------------------------------------
extern "C" void kernel_launch(void* const* d_in, const int* in_sizes, int n_in,
                              void* d_out, int out_size, void* d_ws, size_t ws_size,
                              hipStream_t stream)
{
    const float* x     = (const float*)d_in[0];
    const float* gamma = (const float*)d_in[1];
    float* out = (float*)d_out;

    // d_out doubles as scratch for the Gram partials (SPLIT=64: 50.3 MB
    // < 134.2 MB of d_out); K2 consumes them before K4 overwrites d_out.
    float* part = out;
    float* a1    = (float*)d_ws;                       // 1 MiB
    float* p     = a1 + (size_t)BB * CCH * CCH;        // 1 MiB
    int*   nzcnt = (int*)(p + (size_t)BB * CCH * CCH); // 4 KiB
    int*   nzidx = nzcnt + BB * CCH;                   // 64 KiB
    float* nzval = (float*)(nzidx + BB * CCH * NZCAP); // 64 KiB

    k1_gram_partial<<<dim3(3, BB, SPLIT), 256, 0, stream>>>(x, part);
    k2_reduce      <<<dim3(768),          256, 0, stream>>>(part, a1);
    k3_softmax     <<<dim3(CCH, BB),      256, 0, stream>>>(a1, p, nzcnt, nzidx, nzval);
    k4_out         <<<dim3(NCHUNK, CCH, BB), 256, 0, stream>>>(x, p, nzcnt, nzidx, nzval, gamma, out);
}

// Round 9
// 311.465 us; speedup vs baseline: 1.3572x; 1.0217x over previous
//
#include <hip/hip_runtime.h>
#include <math.h>

// Problem constants (B, C, H, W, D) = (4, 256, 32, 32, 32)
#define CCH   256
#define NTOT  32768                 // H*W*D
#define BB    4
#define SPLIT 64                    // K-split: grid = 3*4*64 = 768 blocks = 3/CU
#define KC    (NTOT / SPLIT)        // 512 k's per block
#define KN    32                    // k-chunk staged in LDS per iteration
#define NSTAGES (KC / KN)           // 16
#define LDK   40                    // LDS row stride in bf16 units (80 B, 16B-aligned rows)
#define NZCAP 16                    // nonzero-list capacity per softmax row

typedef __attribute__((ext_vector_type(8)))  short short8v;   // 8 bf16 = 4 VGPRs
typedef __attribute__((ext_vector_type(16))) float f32x16;    // 32x32 MFMA acc

__device__ inline float4 fma4(float s, float4 a, float4 c) {
    return make_float4(fmaf(s, a.x, c.x), fmaf(s, a.y, c.y),
                       fmaf(s, a.z, c.z), fmaf(s, a.w, c.w));
}

// Split float4 into hi/lo bf16 (both TRUNCATED) and store packed to LDS.
// hi = trunc-bf16(x); lo = trunc-bf16(x - hi). Residual ~2^-16|x| (dropped LL
// term ~2^-16 rel, lo-trunc bias ~2^-24) -- all ~6 orders below the ~3.5e6
// affinity argmin margins. 18 VALU ops per 4 elems (old RNE path: ~28).
__device__ inline void stash4(short* __restrict__ Hp, short* __restrict__ Lp,
                              const float4 v) {
    const unsigned int u0 = __float_as_uint(v.x), u1 = __float_as_uint(v.y);
    const unsigned int u2 = __float_as_uint(v.z), u3 = __float_as_uint(v.w);
    const unsigned int hf0 = u0 & 0xFFFF0000u, hf1 = u1 & 0xFFFF0000u;
    const unsigned int hf2 = u2 & 0xFFFF0000u, hf3 = u3 & 0xFFFF0000u;
    const unsigned int hp0 = (u0 >> 16) | hf1;
    const unsigned int hp1 = (u2 >> 16) | hf3;
    const float l0 = v.x - __uint_as_float(hf0);
    const float l1 = v.y - __uint_as_float(hf1);
    const float l2 = v.z - __uint_as_float(hf2);
    const float l3 = v.w - __uint_as_float(hf3);
    const unsigned int lp0 = (__float_as_uint(l0) >> 16) | (__float_as_uint(l1) & 0xFFFF0000u);
    const unsigned int lp1 = (__float_as_uint(l2) >> 16) | (__float_as_uint(l3) & 0xFFFF0000u);
    *(uint2*)Hp = make_uint2(hp0, hp1);
    *(uint2*)Lp = make_uint2(lp0, lp1);
}

// ---------------------------------------------------------------------------
// K1: partial Gram a1[b] = xf[b] @ xf[b]^T via bf16 split MFMA (HH+HL+LH).
// Symmetric 3-tile scheme: tile0 (0,0) diag, tile1 (0,128) offdiag, tile2
// (128,128) diag. grid (3, B, SPLIT), 256 threads (4 waves), each wave owns a
// 64x64 quadrant of the 128x128 output = 2x2 MFMA tiles of 32x32.
// Staging is software-pipelined: stage t+1's global loads are issued into
// registers right after the write->read barrier, hiding HBM latency under
// stage t's MFMA block (T14 issue-early/write-late pattern).
// Partials (fp32) land in d_out scratch; K2 reduces them (unchanged format).
// ---------------------------------------------------------------------------
__global__ __launch_bounds__(256, 3)
void k1_gram_partial(const float* __restrict__ x, float* __restrict__ part)
{
    const int tile = blockIdx.x;              // 0..2
    const int b    = blockIdx.y;              // 0..3
    const int s    = blockIdx.z;              // 0..SPLIT-1
    const int c0   = (tile == 2) ? 128 : 0;
    const int d0   = (tile == 0) ? 0 : 128;
    const bool diag = (tile != 1);

    const float* __restrict__ xb = x + (size_t)b * CCH * NTOT;
    const int n0 = s * KC;

    // rows [0,128) = A channels (c0+r); rows [128,256) = B channels (d0+r), offdiag only
    __shared__ __align__(16) short sH[256][LDK];
    __shared__ __align__(16) short sL[256][LDK];

    const int tid  = threadIdx.x;
    const int wid  = tid >> 6;      // wave 0..3
    const int wr   = wid >> 1;      // wave row quadrant (0,1)
    const int wc   = wid & 1;       // wave col quadrant (0,1)
    const int lane = tid & 63;
    const int l31  = lane & 31;
    const int kh   = lane >> 5;     // k-half selector (0,1)

    const int lrow = tid >> 3;      // staging row within 32-row group
    const int lk0  = (tid & 7) * 4; // staging k offset (float4)

    f32x16 acc00 = {0.f}, acc01 = {0.f}, acc10 = {0.f}, acc11 = {0.f};

    const int brow0 = diag ? 0 : 128;          // LDS base row for B-operand

    float4 va[4];                  // A-rows staging regs
    float4 vb[4];                  // B-rows staging regs (offdiag only)

    // ---- prologue: load stage 0 into regs ----
#pragma unroll
    for (int it = 0; it < 4; ++it)
        va[it] = *(const float4*)&xb[(size_t)(c0 + it * 32 + lrow) * NTOT + n0 + lk0];
    if (!diag) {
#pragma unroll
        for (int it = 0; it < 4; ++it)
            vb[it] = *(const float4*)&xb[(size_t)(d0 + it * 32 + lrow) * NTOT + n0 + lk0];
    }

    for (int st = 0; st < NSTAGES; ++st) {
        // ---- cvt + write LDS from regs ----
#pragma unroll
        for (int it = 0; it < 4; ++it) {
            const int r = it * 32 + lrow;
            stash4(&sH[r][lk0], &sL[r][lk0], va[it]);
        }
        if (!diag) {
#pragma unroll
            for (int it = 0; it < 4; ++it) {
                const int r = 128 + it * 32 + lrow;
                stash4(&sH[r][lk0], &sL[r][lk0], vb[it]);
            }
        }
        __syncthreads();

        // ---- prefetch stage st+1 into regs (hides HBM under MFMA below) ----
        if (st + 1 < NSTAGES) {
            const int nb2 = n0 + (st + 1) * KN;
#pragma unroll
            for (int it = 0; it < 4; ++it)
                va[it] = *(const float4*)&xb[(size_t)(c0 + it * 32 + lrow) * NTOT + nb2 + lk0];
            if (!diag) {
#pragma unroll
                for (int it = 0; it < 4; ++it)
                    vb[it] = *(const float4*)&xb[(size_t)(d0 + it * 32 + lrow) * NTOT + nb2 + lk0];
            }
        }

        // ---- compute: 2 K-steps of 16, 2x2 tiles, 3 passes each ----
#pragma unroll
        for (int kk = 0; kk < KN; kk += 16) {
            const int koff = kk + kh * 8;
            const int ar0 = wr * 64 + l31;            // A rows (LDS)
            const int br0 = brow0 + wc * 64 + l31;    // B rows (LDS)
            const short8v a0h = *(const short8v*)&sH[ar0     ][koff];
            const short8v a0l = *(const short8v*)&sL[ar0     ][koff];
            const short8v a1h = *(const short8v*)&sH[ar0 + 32][koff];
            const short8v a1l = *(const short8v*)&sL[ar0 + 32][koff];
            const short8v b0h = *(const short8v*)&sH[br0     ][koff];
            const short8v b0l = *(const short8v*)&sL[br0     ][koff];
            const short8v b1h = *(const short8v*)&sH[br0 + 32][koff];
            const short8v b1l = *(const short8v*)&sL[br0 + 32][koff];

            acc00 = __builtin_amdgcn_mfma_f32_32x32x16_bf16(a0h, b0h, acc00, 0, 0, 0);
            acc00 = __builtin_amdgcn_mfma_f32_32x32x16_bf16(a0h, b0l, acc00, 0, 0, 0);
            acc00 = __builtin_amdgcn_mfma_f32_32x32x16_bf16(a0l, b0h, acc00, 0, 0, 0);

            acc01 = __builtin_amdgcn_mfma_f32_32x32x16_bf16(a0h, b1h, acc01, 0, 0, 0);
            acc01 = __builtin_amdgcn_mfma_f32_32x32x16_bf16(a0h, b1l, acc01, 0, 0, 0);
            acc01 = __builtin_amdgcn_mfma_f32_32x32x16_bf16(a0l, b1h, acc01, 0, 0, 0);

            acc10 = __builtin_amdgcn_mfma_f32_32x32x16_bf16(a1h, b0h, acc10, 0, 0, 0);
            acc10 = __builtin_amdgcn_mfma_f32_32x32x16_bf16(a1h, b0l, acc10, 0, 0, 0);
            acc10 = __builtin_amdgcn_mfma_f32_32x32x16_bf16(a1l, b0h, acc10, 0, 0, 0);

            acc11 = __builtin_amdgcn_mfma_f32_32x32x16_bf16(a1h, b1h, acc11, 0, 0, 0);
            acc11 = __builtin_amdgcn_mfma_f32_32x32x16_bf16(a1h, b1l, acc11, 0, 0, 0);
            acc11 = __builtin_amdgcn_mfma_f32_32x32x16_bf16(a1l, b1h, acc11, 0, 0, 0);
        }
        __syncthreads();                       // protect LDS before next overwrite
    }

    // ---- write 128x128 fp32 partial tile; C/D map: col=l&31, row=(q&3)+8(q>>2)+4*kh
    float* __restrict__ pdst =
        part + (((size_t)s * BB + b) * 3 + tile) * (128 * 128);
#define WRITE_TILE(ACC, TI, TJ)                                              \
    _Pragma("unroll")                                                        \
    for (int q = 0; q < 16; ++q) {                                           \
        const int row = wr * 64 + (TI) * 32 + (q & 3) + 8 * (q >> 2) + 4 * kh; \
        const int col = wc * 64 + (TJ) * 32 + l31;                           \
        pdst[row * 128 + col] = (ACC)[q];                                    \
    }
    WRITE_TILE(acc00, 0, 0)
    WRITE_TILE(acc01, 0, 1)
    WRITE_TILE(acc10, 1, 0)
    WRITE_TILE(acc11, 1, 1)
#undef WRITE_TILE
}

// ---------------------------------------------------------------------------
// K2: reduce the SPLIT partials -> a1[b][c][d] (in ws), mirroring tile 1.
// ---------------------------------------------------------------------------
__global__ __launch_bounds__(256)
void k2_reduce(const float* __restrict__ part, float* __restrict__ a1)
{
    const int gi   = blockIdx.x * 256 + threadIdx.x;   // 0 .. 196607
    const int ld   = gi & 127;
    const int lc   = (gi >> 7) & 127;
    const int t    = gi >> 14;                         // 0..11
    const int tile = t % 3;
    const int b    = t / 3;

    const size_t off    = ((size_t)b * 3 + tile) * (128 * 128) + lc * 128 + ld;
    const size_t stride = (size_t)BB * 3 * (128 * 128);
    float sum = 0.f;
#pragma unroll 8
    for (int s = 0; s < SPLIT; ++s) sum += part[off + s * stride];

    const int c0 = (tile == 2) ? 128 : 0;
    const int d0 = (tile == 0) ? 0 : 128;
    const int c = c0 + lc, d = d0 + ld;
    a1[((size_t)b << 16) + (c << 8) + d] = sum;
    if (tile == 1)                                      // mirror (symmetric)
        a1[((size_t)b << 16) + ((128 + ld) << 8) + lc] = sum;
}

// ---------------------------------------------------------------------------
// K3: one block per (b, row c): affinity row = a1[c,:] @ a1, then the
// reference's exact softmax path; also emits nonzero list for K4.
// ---------------------------------------------------------------------------
__global__ __launch_bounds__(256)
void k3_softmax(const float* __restrict__ a1, float* __restrict__ p,
                int* __restrict__ nzcnt, int* __restrict__ nzidx,
                float* __restrict__ nzval)
{
    const int c = blockIdx.x;
    const int b = blockIdx.y;
    const int bc = (b << 8) + c;
    const float* __restrict__ A = a1 + ((size_t)b << 16);

    __shared__ float arow[256];
    __shared__ float red[256];
    const int e = threadIdx.x;
    arow[e] = A[(c << 8) + e];
    __syncthreads();

    float aff = 0.f;
#pragma unroll 8
    for (int d = 0; d < 256; ++d)
        aff = fmaf(arow[d], A[(d << 8) + e], aff);

    red[e] = aff; __syncthreads();
    for (int s2 = 128; s2 > 0; s2 >>= 1) {
        if (e < s2) red[e] = fmaxf(red[e], red[e + s2]);
        __syncthreads();
    }
    const float M = red[0];
    __syncthreads();

    const float an = M - aff;
    red[e] = an; __syncthreads();
    for (int s2 = 128; s2 > 0; s2 >>= 1) {
        if (e < s2) red[e] = fmaxf(red[e], red[e + s2]);
        __syncthreads();
    }
    const float m2 = red[0];
    __syncthreads();

    const float ex = expf(an - m2);
    red[e] = ex; __syncthreads();
    for (int s2 = 128; s2 > 0; s2 >>= 1) {
        if (e < s2) red[e] += red[e + s2];
        __syncthreads();
    }
    const float Z = red[0];
    const float pv = ex / Z;
    p[((size_t)bc << 8) + e] = pv;

    __syncthreads();
    arow[e] = pv;
    __syncthreads();
    if (e == 0) {
        int k = 0;
        for (int d = 0; d < 256; ++d) {
            const float v = arow[d];
            if (v > 0.f) {
                if (k < NZCAP) { nzidx[bc * NZCAP + k] = d; nzval[bc * NZCAP + k] = v; }
                ++k;
            }
        }
        nzcnt[bc] = k;
    }
}

// ---------------------------------------------------------------------------
// K4: out = gamma * (p @ xf) + x via the nonzero list (typically 1 entry).
// ---------------------------------------------------------------------------
#define NCHUNK 8
#define CH4    (NTOT / NCHUNK / 4)   // 1024 float4 per chunk

__global__ __launch_bounds__(256)
void k4_out(const float* __restrict__ x, const float* __restrict__ p,
            const int* __restrict__ nzcnt, const int* __restrict__ nzidx,
            const float* __restrict__ nzval,
            const float* __restrict__ gamma, float* __restrict__ out)
{
    const int ch = blockIdx.x;   // 0..7
    const int c  = blockIdx.y;   // 0..255
    const int b  = blockIdx.z;   // 0..3
    const int bc = (b << 8) + c;
    const float* __restrict__ xb = x + (size_t)b * CCH * NTOT;

    const int tid = threadIdx.x;
    const size_t nb4 = (size_t)ch * CH4;
    float4 acc0 = make_float4(0, 0, 0, 0);
    float4 acc1 = acc0, acc2 = acc0, acc3 = acc0;

    const int k = nzcnt[bc];
    if (k <= NZCAP) {
        for (int j = 0; j < k; ++j) {        // ascending d, matches ref order
            const int   d  = nzidx[bc * NZCAP + j];
            const float sv = nzval[bc * NZCAP + j];
            const float4* __restrict__ r =
                (const float4*)(xb + (size_t)d * NTOT) + nb4;
            acc0 = fma4(sv, r[tid],       acc0);
            acc1 = fma4(sv, r[tid + 256], acc1);
            acc2 = fma4(sv, r[tid + 512], acc2);
            acc3 = fma4(sv, r[tid + 768], acc3);
        }
    } else {                                  // dense fallback (always correct)
        for (int d = 0; d < 256; ++d) {
            const float sv = p[((size_t)bc << 8) + d];
            if (sv != 0.f) {
                const float4* __restrict__ r =
                    (const float4*)(xb + (size_t)d * NTOT) + nb4;
                acc0 = fma4(sv, r[tid],       acc0);
                acc1 = fma4(sv, r[tid + 256], acc1);
                acc2 = fma4(sv, r[tid + 512], acc2);
                acc3 = fma4(sv, r[tid + 768], acc3);
            }
        }
    }

    const float g = gamma[0];
    const float4* __restrict__ xr = (const float4*)(xb + (size_t)c * NTOT) + nb4;
    float4* __restrict__ o =
        (float4*)(out + ((size_t)b * CCH + c) * NTOT) + nb4;
    o[tid]       = fma4(g, acc0, xr[tid]);
    o[tid + 256] = fma4(g, acc1, xr[tid + 256]);
    o[tid + 512] = fma4(g, acc2, xr[tid + 512]);
    o[tid + 768] = fma4(g, acc3, xr[tid + 768]);
}

// ---------------------------------------------------------------------------
extern "C" void kernel_launch(void* const* d_in, const int* in_sizes, int n_in,
                              void* d_out, int out_size, void* d_ws, size_t ws_size,
                              hipStream_t stream)
{
    const float* x     = (const float*)d_in[0];
    const float* gamma = (const float*)d_in[1];
    float* out = (float*)d_out;

    // d_out doubles as scratch for the Gram partials (SPLIT=64: 50.3 MB
    // < 134.2 MB of d_out); K2 consumes them before K4 overwrites d_out.
    float* part = out;
    float* a1    = (float*)d_ws;                       // 1 MiB
    float* p     = a1 + (size_t)BB * CCH * CCH;        // 1 MiB
    int*   nzcnt = (int*)(p + (size_t)BB * CCH * CCH); // 4 KiB
    int*   nzidx = nzcnt + BB * CCH;                   // 64 KiB
    float* nzval = (float*)(nzidx + BB * CCH * NZCAP); // 64 KiB

    k1_gram_partial<<<dim3(3, BB, SPLIT), 256, 0, stream>>>(x, part);
    k2_reduce      <<<dim3(768),          256, 0, stream>>>(part, a1);
    k3_softmax     <<<dim3(CCH, BB),      256, 0, stream>>>(a1, p, nzcnt, nzidx, nzval);
    k4_out         <<<dim3(NCHUNK, CCH, BB), 256, 0, stream>>>(x, p, nzcnt, nzidx, nzval, gamma, out);
}